// Round 4
// baseline (384.919 us; speedup 1.0000x reference)
//
#include <hip/hip_runtime.h>

#define NT 256

constexpr int Bg   = 8192;      // graphs
constexpr int NPG  = 40;        // nodes per graph
constexpr int EPG  = 640;       // edges per graph
constexpr int IN_  = 64;
constexpr int HID  = 32;
constexpr int K1   = 20;
constexpr int K2   = 10;
constexpr int OUTC = 10;
constexpr int NE   = Bg * NPG * 16;   // total edges
constexpr int SH   = 36;        // padded 32-wide row stride (floats)
constexpr float EPSF = 1e-15f;

#define FMA4(acc, a, b) do { \
    float _s = (a); \
    acc.x = fmaf(_s, (b).x, acc.x); \
    acc.y = fmaf(_s, (b).y, acc.y); \
    acc.z = fmaf(_s, (b).z, acc.z); \
    acc.w = fmaf(_s, (b).w, acc.w); } while (0)

__device__ __forceinline__ float wave_red(float v) {
#pragma unroll
    for (int off = 32; off > 0; off >>= 1) v += __shfl_down(v, off, 64);
    return v;
}

// LDS overlay map (floats):
//  sA_  [1600] : A raw (iv0-iv6) ; first 400 become A2 = S^T A S raw (iv7+)
//  bufH [1440] : H=XW1 (iv1-3) ; X2 [0..720) (iv7+, then X2new iv C+) ;
//                XW2r [720..1440) (iv8+)
//  bufXd[1440] : Xd (iv3-7) ; XW3r [0..360), XW3o [360..720) (ivI+) ;
//                X3 [720..1080) (ivF+) ; X4 [1080..1440) (ivJ+)
//  bufS [800]  : S1 (iv4-7) ; S2 [0..200), AS2 [200..400), A3 [400..500),
//                SS2 [500..600) (ivD+)
//  bufAS[800]  : AS=A@S (iv6-7) ; XW2o [0..720) (iv8+)
//  sSS  [400]  : S^T S (iv6-8)
__global__ __launch_bounds__(NT, 6)
void mincut_fused(const float* __restrict__ x, const int* __restrict__ ei,
                  const float* __restrict__ w_c1, const float* __restrict__ b_c1,
                  const float* __restrict__ w_p1, const float* __restrict__ b_p1,
                  const float* __restrict__ w2r_, const float* __restrict__ b2_,
                  const float* __restrict__ w2o_,
                  const float* __restrict__ w_p2, const float* __restrict__ b_p2,
                  const float* __restrict__ w3r_, const float* __restrict__ b3_,
                  const float* __restrict__ w3o_,
                  const float* __restrict__ w_l1, const float* __restrict__ b_l1,
                  const float* __restrict__ w_l2, const float* __restrict__ b_l2,
                  float* __restrict__ out, float* __restrict__ wsg)
{
    __shared__ __align__(16) float sA_[NPG * NPG];   // 1600
    __shared__ __align__(16) float bufH[NPG * SH];   // 1440
    __shared__ __align__(16) float bufXd[NPG * SH];  // 1440
    __shared__ __align__(16) float bufS[NPG * K1];   // 800
    __shared__ __align__(16) float bufAS[NPG * K1];  // 800
    __shared__ __align__(16) float sSS[K1 * K1];     // 400
    __shared__ __align__(16) float sdinv[NPG];
    __shared__ __align__(16) float srowsA[NPG];
    __shared__ __align__(16) float srowm[NPG];
    __shared__ __align__(16) float sden[NPG];
    __shared__ __align__(16) float sred1[2];
    __shared__ __align__(16) float sred2[2];
    __shared__ __align__(16) float sc[8];

    float* sA2  = sA_;           // 20x20
    float* sX2  = bufH;          // 20xSH (X2, then X2new)
    float* sW2r = bufH + 720;    // 20xSH (X2 @ w2r)
    float* sW2o = bufAS;         // 20xSH (X2 @ w2o)
    float* sS2  = bufS;          // 20x10
    float* sAS2 = bufS + 200;    // 20x10
    float* sA3  = bufS + 400;    // 10x10
    float* sSS2 = bufS + 500;    // 10x10
    float* sW3r = bufXd;         // 10xSH
    float* sW3o = bufXd + 360;   // 10xSH
    float* sX3  = bufXd + 720;   // 10xSH
    float* sX4  = bufXd + 1080;  // 10xSH

    const int g    = blockIdx.x;
    const int tid  = threadIdx.x;
    const int lane = tid & 63;
    const int wid  = tid >> 6;

    // ---------------- iv0: zero A, load edges to regs ----------------
    int er0, ec0, er1, ec1, er2 = -1, ec2 = 0;
    {
        const int eb = g * EPG, nb = g * NPG;
        const int* srcp = ei;
        const int* dstp = ei + NE;
        int e = eb + tid;
        er0 = srcp[e] - nb; ec0 = dstp[e] - nb;
        e += NT;
        er1 = srcp[e] - nb; ec1 = dstp[e] - nb;
        if (tid + 2 * NT < EPG) {
            e += NT;
            er2 = srcp[e] - nb; ec2 = dstp[e] - nb;
        }
    }
    for (int i = tid; i < NPG * NPG; i += NT) sA_[i] = 0.f;
    __syncthreads();

    // ------- iv1: adj scatter + H = X @ W1 (X, W1 from global) -------
    atomicAdd(&sA_[er0 * NPG + ec0], 1.f);
    atomicAdd(&sA_[er1 * NPG + ec1], 1.f);
    if (er2 >= 0) atomicAdd(&sA_[er2 * NPG + ec2], 1.f);

    if (tid < 160) {                 // 20 row-pairs x 8 col-quads
        int np = tid >> 3, fq = tid & 7;
        int n0 = 2 * np, n1 = n0 + 1;
        const float4* x0 = (const float4*)(x + (size_t)g * (NPG * IN_) + n0 * IN_);
        const float4* x1 = (const float4*)(x + (size_t)g * (NPG * IN_) + n1 * IN_);
        const float4* wg = (const float4*)w_c1;
        float4 acc0 = {0.f,0.f,0.f,0.f}, acc1 = {0.f,0.f,0.f,0.f};
#pragma unroll 4
        for (int kk = 0; kk < IN_ / 4; kk++) {
            float4 a0 = x0[kk], a1 = x1[kk];
            float4 w0 = wg[(4*kk+0)*8 + fq];
            float4 w1 = wg[(4*kk+1)*8 + fq];
            float4 w2 = wg[(4*kk+2)*8 + fq];
            float4 w3 = wg[(4*kk+3)*8 + fq];
            FMA4(acc0, a0.x, w0); FMA4(acc0, a0.y, w1);
            FMA4(acc0, a0.z, w2); FMA4(acc0, a0.w, w3);
            FMA4(acc1, a1.x, w0); FMA4(acc1, a1.y, w1);
            FMA4(acc1, a1.z, w2); FMA4(acc1, a1.w, w3);
        }
        ((float4*)(bufH + n0 * SH))[fq] = acc0;
        ((float4*)(bufH + n1 * SH))[fq] = acc1;
    }
    __syncthreads();

    // ---------------- iv2: degrees ----------------
    if (tid < NPG) {                 // col sums -> dinv
        float s = 0.f;
#pragma unroll
        for (int r = 0; r < NPG; r++) s += sA_[r * NPG + tid];
        sdinv[tid] = rsqrtf(s + 1.f);
    } else if (tid >= 64 && tid < 64 + NPG) {   // row sums (d_flat, raw A)
        int n = tid - 64; float s = 0.f;
#pragma unroll
        for (int m = 0; m < NPG; m++) s += sA_[n * NPG + m];
        srowsA[n] = s;
    }
    __syncthreads();

    // ------- iv3: Xd = relu(D^-1/2 (A+I) D^-1/2 H + b1) [f2 A reads] -------
    if (tid < 160) {
        int cp = tid >> 3, fq = tid & 7;
        int c0 = 2 * cp, c1 = c0 + 1;
        float4 acc0 = {0.f,0.f,0.f,0.f}, acc1 = {0.f,0.f,0.f,0.f};
#pragma unroll 8
        for (int r = 0; r < NPG; r++) {
            float2 a2 = *(const float2*)&sA_[r * NPG + c0];
            float dv = sdinv[r];
            float4 b = ((const float4*)(bufH + r * SH))[fq];
            FMA4(acc0, a2.x * dv, b);
            FMA4(acc1, a2.y * dv, b);
        }
        float4 bb = ((const float4*)b_c1)[fq];
        float4 h0 = ((const float4*)(bufH + c0 * SH))[fq];
        float4 h1 = ((const float4*)(bufH + c1 * SH))[fq];
        float d0 = sdinv[c0], d1 = sdinv[c1];
        float4 r0, r1;
        r0.x = fmaxf(fmaf(d0, fmaf(d0, h0.x, acc0.x), bb.x), 0.f);
        r0.y = fmaxf(fmaf(d0, fmaf(d0, h0.y, acc0.y), bb.y), 0.f);
        r0.z = fmaxf(fmaf(d0, fmaf(d0, h0.z, acc0.z), bb.z), 0.f);
        r0.w = fmaxf(fmaf(d0, fmaf(d0, h0.w, acc0.w), bb.w), 0.f);
        r1.x = fmaxf(fmaf(d1, fmaf(d1, h1.x, acc1.x), bb.x), 0.f);
        r1.y = fmaxf(fmaf(d1, fmaf(d1, h1.y, acc1.y), bb.y), 0.f);
        r1.z = fmaxf(fmaf(d1, fmaf(d1, h1.z, acc1.z), bb.z), 0.f);
        r1.w = fmaxf(fmaf(d1, fmaf(d1, h1.w, acc1.w), bb.w), 0.f);
        ((float4*)(bufXd + c0 * SH))[fq] = r0;
        ((float4*)(bufXd + c1 * SH))[fq] = r1;
    }
    __syncthreads();

    // ---------------- iv4: S1 logits = Xd @ Wp1 + bp1 ----------------
    if (tid < 100) {                 // 20 row-pairs x 5 l-quads
        int np = tid / 5, lq = tid - np * 5;
        int n0 = 2 * np, n1 = n0 + 1;
        const float4* wg = (const float4*)w_p1;
        float4 bb = ((const float4*)b_p1)[lq];
        float4 acc0 = bb, acc1 = bb;
#pragma unroll 8
        for (int k = 0; k < HID; k++) {
            float a0 = bufXd[n0 * SH + k];
            float a1 = bufXd[n1 * SH + k];
            float4 w = wg[k * 5 + lq];
            FMA4(acc0, a0, w);
            FMA4(acc1, a1, w);
        }
        ((float4*)(bufS + n0 * K1))[lq] = acc0;
        ((float4*)(bufS + n1 * K1))[lq] = acc1;
    }
    __syncthreads();

    // ---------------- iv5: row softmax (K1) ----------------
    if (tid < NPG) {
        float* row = bufS + tid * K1;
        float v[K1]; float m = -3.0e38f;
#pragma unroll
        for (int k = 0; k < K1; k++) { v[k] = row[k]; m = fmaxf(m, v[k]); }
        float ssum = 0.f;
#pragma unroll
        for (int k = 0; k < K1; k++) { v[k] = __expf(v[k] - m); ssum += v[k]; }
        float inv = 1.f / ssum;
#pragma unroll
        for (int k = 0; k < K1; k++) row[k] = v[k] * inv;
    }
    __syncthreads();

    // ---------------- iv6: AS = A @ S [f4 A-rows] ; SS = S^T S [f2] --------
    if (tid < 100) {                 // AS: 20 row-pairs x 5 quads
        int np = tid / 5, lq = tid - np * 5;
        int n0 = 2 * np, n1 = n0 + 1;
        const float4* sb = (const float4*)bufS;
        float4 acc0 = {0.f,0.f,0.f,0.f}, acc1 = {0.f,0.f,0.f,0.f};
#pragma unroll
        for (int m4 = 0; m4 < NPG / 4; m4++) {
            float4 a0 = *(const float4*)&sA_[n0 * NPG + 4 * m4];
            float4 a1 = *(const float4*)&sA_[n1 * NPG + 4 * m4];
            float4 b0 = sb[(4*m4+0)*5 + lq];
            float4 b1 = sb[(4*m4+1)*5 + lq];
            float4 b2v = sb[(4*m4+2)*5 + lq];
            float4 b3v = sb[(4*m4+3)*5 + lq];
            FMA4(acc0, a0.x, b0); FMA4(acc0, a0.y, b1);
            FMA4(acc0, a0.z, b2v); FMA4(acc0, a0.w, b3v);
            FMA4(acc1, a1.x, b0); FMA4(acc1, a1.y, b1);
            FMA4(acc1, a1.z, b2v); FMA4(acc1, a1.w, b3v);
        }
        ((float4*)(bufAS + n0 * K1))[lq] = acc0;
        ((float4*)(bufAS + n1 * K1))[lq] = acc1;
    } else if (tid < 150) {          // SS: 10 k-pairs x 5 quads
        int oo = tid - 100;
        int kp = oo / 5, lq = oo - kp * 5;
        int k0 = 2 * kp, k1 = k0 + 1;
        float4 acc0 = {0.f,0.f,0.f,0.f}, acc1 = {0.f,0.f,0.f,0.f};
#pragma unroll 8
        for (int n = 0; n < NPG; n++) {
            float2 s2v = *(const float2*)&bufS[n * K1 + k0];
            float4 b = ((const float4*)(bufS + n * K1))[lq];
            FMA4(acc0, s2v.x, b);
            FMA4(acc1, s2v.y, b);
        }
        ((float4*)(sSS + k0 * K1))[lq] = acc0;
        ((float4*)(sSS + k1 * K1))[lq] = acc1;
    }
    __syncthreads();

    // --- iv7: A2 = S^T AS ; X2 = S^T Xd ; den1 terms ; SS-Frob (wave3) ----
    if (tid < 50) {                  // A2: 10 k-pairs x 5 quads
        int kp = tid / 5, lq = tid - kp * 5;
        int k0 = 2 * kp, k1 = k0 + 1;
        float4 acc0 = {0.f,0.f,0.f,0.f}, acc1 = {0.f,0.f,0.f,0.f};
#pragma unroll 8
        for (int n = 0; n < NPG; n++) {
            float2 s2v = *(const float2*)&bufS[n * K1 + k0];
            float4 b = ((const float4*)(bufAS + n * K1))[lq];
            FMA4(acc0, s2v.x, b);
            FMA4(acc1, s2v.y, b);
        }
        ((float4*)(sA2 + k0 * K1))[lq] = acc0;
        ((float4*)(sA2 + k1 * K1))[lq] = acc1;
    } else if (tid < 130) {          // X2: 10 k-pairs x 8 f-quads
        int oo = tid - 50;
        int kp = oo >> 3, fq = oo & 7;
        int k0 = 2 * kp, k1 = k0 + 1;
        float4 acc0 = {0.f,0.f,0.f,0.f}, acc1 = {0.f,0.f,0.f,0.f};
#pragma unroll 8
        for (int n = 0; n < NPG; n++) {
            float2 s2v = *(const float2*)&bufS[n * K1 + k0];
            float4 b = ((const float4*)(bufXd + n * SH))[fq];
            FMA4(acc0, s2v.x, b);
            FMA4(acc1, s2v.y, b);
        }
        ((float4*)(sX2 + k0 * SH))[fq] = acc0;
        ((float4*)(sX2 + k1 * SH))[fq] = acc1;
    } else if (tid < 170) {          // den1 terms
        int n = tid - 130;
        float s2 = 0.f;
#pragma unroll
        for (int k = 0; k < K1; k++) { float v = bufS[n * K1 + k]; s2 = fmaf(v, v, s2); }
        sden[n] = srowsA[n] * s2;
    } else if (wid == 3) {           // ||SS||_F^2 -> sc[2]
        float v = 0.f;
        for (int i = lane; i < K1 * K1; i += 64) { float t = sSS[i]; v = fmaf(t, t, v); }
        v = wave_red(v); if (lane == 0) sc[2] = v;
    }
    __syncthreads();

    // --- iv8: ortho1 (w0,w1) ; trace1+rownorm1 (w2) ; den1-red (w3) ;
    //          then all threads: XW2r = X2@w2r, XW2o = X2@w2o --------------
    if (wid < 2) {
        float rn = 1.f / sqrtf(sc[2]);
        const float isk = 0.22360679774997896f;   // 1/sqrt(20)
        float p = 0.f;
        for (int o = tid; o < K1 * K1; o += 128) {
            int k = o / K1, l = o - k * K1;
            float v = sSS[o] * rn - ((k == l) ? isk : 0.f);
            p = fmaf(v, v, p);
        }
        p = wave_red(p);
        if (lane == 0) sred1[wid] = p;
    } else if (wid == 2) {
        float v = (lane < K1) ? sA2[lane * (K1 + 1)] : 0.f;
        v = wave_red(v); if (lane == 0) sc[0] = v;          // num1 = trace
        if (lane < K1) {            // row norms of diag-zeroed A2 (raw kept)
            float s = 0.f;
#pragma unroll
            for (int l = 0; l < K1; l++) s += sA2[lane * K1 + l];
            s -= sA2[lane * (K1 + 1)];
            srowm[lane] = 1.f / (sqrtf(s) + EPSF);
        }
    } else {
        float v = (lane < NPG) ? sden[lane] : 0.f;
        v = wave_red(v); if (lane == 0) sc[1] = v;          // den1
    }
    for (int o = tid; o < 320; o += NT) {    // 1-row x 8fq, two matmuls
        bool first = (o < 160);
        int oo = first ? o : o - 160;
        int n = oo >> 3, fq = oo & 7;
        const float4* wg = (const float4*)(first ? w2r_ : w2o_);
        float4 acc = {0.f,0.f,0.f,0.f};
#pragma unroll 8
        for (int k = 0; k < HID; k++) {
            float a = sX2[n * SH + k];
            FMA4(acc, a, wg[k * 8 + fq]);
        }
        if (first) ((float4*)(sW2r + n * SH))[fq] = acc;
        else       ((float4*)(sW2o + n * SH))[fq] = acc;
    }
    __syncthreads();

    // --- ivC: X2' = relu(adj1n @ XW2r + XW2o + b2)  [norm folded, diag=0] --
    if (tid < 80) {
        int kp = tid >> 3, fq = tid & 7;
        int k0 = 2 * kp, k1 = k0 + 1;
        float4 acc0 = {0.f,0.f,0.f,0.f}, acc1 = {0.f,0.f,0.f,0.f};
#pragma unroll
        for (int l = 0; l < K1; l++) {
            float rl = srowm[l];
            float a0 = (l == k0) ? 0.f : sA2[k0 * K1 + l];
            float a1 = (l == k1) ? 0.f : sA2[k1 * K1 + l];
            float4 w = ((const float4*)(sW2r + l * SH))[fq];
            FMA4(acc0, a0 * rl, w);
            FMA4(acc1, a1 * rl, w);
        }
        float4 bb = ((const float4*)b2_)[fq];
        float4 o0 = ((const float4*)(sW2o + k0 * SH))[fq];
        float4 o1 = ((const float4*)(sW2o + k1 * SH))[fq];
        float rk0 = srowm[k0], rk1 = srowm[k1];
        float4 r0, r1;
        r0.x = fmaxf(fmaf(rk0, acc0.x, o0.x + bb.x), 0.f);
        r0.y = fmaxf(fmaf(rk0, acc0.y, o0.y + bb.y), 0.f);
        r0.z = fmaxf(fmaf(rk0, acc0.z, o0.z + bb.z), 0.f);
        r0.w = fmaxf(fmaf(rk0, acc0.w, o0.w + bb.w), 0.f);
        r1.x = fmaxf(fmaf(rk1, acc1.x, o1.x + bb.x), 0.f);
        r1.y = fmaxf(fmaf(rk1, acc1.y, o1.y + bb.y), 0.f);
        r1.z = fmaxf(fmaf(rk1, acc1.z, o1.z + bb.z), 0.f);
        r1.w = fmaxf(fmaf(rk1, acc1.w, o1.w + bb.w), 0.f);
        ((float4*)(sX2 + k0 * SH))[fq] = r0;    // overwrite X2 with X2'
        ((float4*)(sX2 + k1 * SH))[fq] = r1;
    }
    __syncthreads();

    // ---------------- ivD: S2 logits ----------------
    if (tid < K1 * K2) {
        int n = tid / K2, q = tid - n * K2;
        float acc = b_p2[q];
#pragma unroll 8
        for (int j = 0; j < HID; j++) acc = fmaf(sX2[n * SH + j], w_p2[j * K2 + q], acc);
        sS2[tid] = acc;
    }
    __syncthreads();

    // ---------------- ivE: softmax2 ----------------
    if (tid < K1) {
        float* row = sS2 + tid * K2;
        float v[K2]; float m = -3.0e38f;
#pragma unroll
        for (int q = 0; q < K2; q++) { v[q] = row[q]; m = fmaxf(m, v[q]); }
        float ssum = 0.f;
#pragma unroll
        for (int q = 0; q < K2; q++) { v[q] = __expf(v[q] - m); ssum += v[q]; }
        float inv = 1.f / ssum;
#pragma unroll
        for (int q = 0; q < K2; q++) row[q] = v[q] * inv;
    }
    __syncthreads();

    // --- ivF: AS2 = adj1n@S2 [folded] ; SS2 ; X3 = S2^T X2' ; den2 terms ---
    for (int o = tid; o < 400; o += NT) {
        if (o < 200) {
            int n = o / K2, l = o - n * K2;
            float acc = 0.f;
#pragma unroll
            for (int m = 0; m < K1; m++) {
                float a = (m == n) ? 0.f : sA2[n * K1 + m];
                acc = fmaf(a * srowm[m], sS2[m * K2 + l], acc);
            }
            sAS2[n * K2 + l] = acc * srowm[n];
        } else if (o < 300) {
            int oo = o - 200; int k = oo / K2, l = oo - k * K2;
            float acc = 0.f;
#pragma unroll
            for (int n = 0; n < K1; n++) acc = fmaf(sS2[n * K2 + k], sS2[n * K2 + l], acc);
            sSS2[k * K2 + l] = acc;
        } else if (o < 380) {
            int oo = o - 300; int k = oo >> 3, fq = oo & 7;
            float4 acc = {0.f, 0.f, 0.f, 0.f};
#pragma unroll
            for (int n = 0; n < K1; n++) {
                float a = sS2[n * K2 + k];
                float4 b = ((const float4*)(sX2 + n * SH))[fq];
                FMA4(acc, a, b);
            }
            ((float4*)(sX3 + k * SH))[fq] = acc;
        } else {
            int n = o - 380;          // d_flat of adj1n times ||S2 row||^2
            float da = 0.f, s2 = 0.f;
#pragma unroll
            for (int l = 0; l < K1; l++) {
                float a = (l == n) ? 0.f : sA2[n * K1 + l];
                da = fmaf(a, srowm[l], da);
            }
            da *= srowm[n];
#pragma unroll
            for (int q = 0; q < K2; q++) { float v = sS2[n * K2 + q]; s2 = fmaf(v, v, s2); }
            sden[n] = da * s2;
        }
    }
    __syncthreads();

    // --- ivG: out_adj2 = S2^T AS2 ; den2-red (w2) ; SS2-Frob (w3) ---------
    if (tid < K2 * K2) {
        int k = tid / K2, l = tid - k * K2;
        float acc = 0.f;
#pragma unroll
        for (int n = 0; n < K1; n++) acc = fmaf(sS2[n * K2 + k], sAS2[n * K2 + l], acc);
        sA3[tid] = acc;
    } else if (wid == 2) {
        float v = (lane < K1) ? sden[lane] : 0.f;
        v = wave_red(v); if (lane == 0) sc[5] = v;          // den2
    } else if (wid == 3) {
        float v = 0.f;
        for (int i = lane; i < K2 * K2; i += 64) { float t = sSS2[i]; v = fmaf(t, t, v); }
        v = wave_red(v); if (lane == 0) sc[6] = v;          // ||SS2||_F^2
    }
    __syncthreads();

    // --- ivH: ortho2 (w0) ; trace2 + rownorm2 (w1) ------------------------
    if (wid == 0) {
        float rn = 1.f / sqrtf(sc[6]);
        const float isk = 0.31622776601683794f;   // 1/sqrt(10)
        float p = 0.f;
        for (int i = lane; i < K2 * K2; i += 64) {
            int k = i / K2, l = i - k * K2;
            float v = sSS2[i] * rn - ((k == l) ? isk : 0.f);
            p = fmaf(v, v, p);
        }
        p = wave_red(p);
        if (lane == 0) sred2[0] = p;
    } else if (wid == 1) {
        float v = (lane < K2) ? sA3[lane * (K2 + 1)] : 0.f;
        v = wave_red(v); if (lane == 0) sc[4] = v;          // num2 = trace
        if (lane < K2) {
            float s = 0.f;
#pragma unroll
            for (int l = 0; l < K2; l++) s += sA3[lane * K2 + l];
            s -= sA3[lane * (K2 + 1)];
            srowm[lane] = 1.f / (sqrtf(s) + EPSF);
        }
    }
    __syncthreads();

    // --- ivI: XW3r = X3@w3r ; XW3o = X3@w3o ; loss write ------------------
    if (tid < 160) {
        bool first = (tid < 80);
        int oo = first ? tid : tid - 80;
        int n = oo >> 3, fq = oo & 7;
        const float4* wg = (const float4*)(first ? w3r_ : w3o_);
        float4 acc = {0.f,0.f,0.f,0.f};
#pragma unroll 8
        for (int k = 0; k < HID; k++) {
            float a = sX3[n * SH + k];
            FMA4(acc, a, wg[k * 8 + fq]);
        }
        if (first) ((float4*)(sW3r + n * SH))[fq] = acc;
        else       ((float4*)(sW3o + n * SH))[fq] = acc;
    } else if (tid == 200) {
        float o1 = sqrtf(sred1[0] + sred1[1]);
        float o2 = sqrtf(sred2[0]);
        wsg[g] = -(sc[0] / sc[1]) + o1 - (sc[4] / sc[5]) + o2;
    }
    __syncthreads();

    // --- ivJ: X4 = adj2n @ XW3r + XW3o + b3 [folded norm, diag=0] ---------
    if (tid < 40) {
        int kp = tid >> 3, fq = tid & 7;
        int k0 = 2 * kp, k1 = k0 + 1;
        float4 acc0 = {0.f,0.f,0.f,0.f}, acc1 = {0.f,0.f,0.f,0.f};
#pragma unroll
        for (int l = 0; l < K2; l++) {
            float rl = srowm[l];
            float a0 = (l == k0) ? 0.f : sA3[k0 * K2 + l];
            float a1 = (l == k1) ? 0.f : sA3[k1 * K2 + l];
            float4 w = ((const float4*)(sW3r + l * SH))[fq];
            FMA4(acc0, a0 * rl, w);
            FMA4(acc1, a1 * rl, w);
        }
        float4 bb = ((const float4*)b3_)[fq];
        float4 o0 = ((const float4*)(sW3o + k0 * SH))[fq];
        float4 o1 = ((const float4*)(sW3o + k1 * SH))[fq];
        float rk0 = srowm[k0], rk1 = srowm[k1];
        float4 r0, r1;
        r0.x = fmaf(rk0, acc0.x, o0.x + bb.x);
        r0.y = fmaf(rk0, acc0.y, o0.y + bb.y);
        r0.z = fmaf(rk0, acc0.z, o0.z + bb.z);
        r0.w = fmaf(rk0, acc0.w, o0.w + bb.w);
        r1.x = fmaf(rk1, acc1.x, o1.x + bb.x);
        r1.y = fmaf(rk1, acc1.y, o1.y + bb.y);
        r1.z = fmaf(rk1, acc1.z, o1.z + bb.z);
        r1.w = fmaf(rk1, acc1.w, o1.w + bb.w);
        ((float4*)(sX4 + k0 * SH))[fq] = r0;
        ((float4*)(sX4 + k1 * SH))[fq] = r1;
    }
    __syncthreads();

    // --- ivK: mean pool + MLP head, single wave, shuffle-based ------------
    if (wid == 0) {
        int f = lane & 31;
        float pool = 0.f;
#pragma unroll
        for (int n = 0; n < K2; n++) pool += sX4[n * SH + f];
        pool *= (1.f / K2);
        float acc = b_l1[f];
#pragma unroll
        for (int j = 0; j < HID; j++)
            acc = fmaf(__shfl(pool, j, 64), w_l1[j * HID + f], acc);
        float t1 = fmaxf(acc, 0.f);
        int o = (lane < OUTC) ? lane : 0;
        float acc2 = b_l2[o];
#pragma unroll
        for (int j = 0; j < HID; j++)
            acc2 = fmaf(__shfl(t1, j, 64), w_l2[j * OUTC + o], acc2);
        if (lane < OUTC) out[(size_t)g * OUTC + lane] = acc2;
    }
}

__global__ void loss_reduce(const float* __restrict__ wsg, float* __restrict__ out)
{
    __shared__ float sred[4];
    int tid = threadIdx.x;
    float s = 0.f;
    for (int i = tid; i < Bg; i += NT) s += wsg[i];
    s = wave_red(s);
    if ((tid & 63) == 0) sred[tid >> 6] = s;
    __syncthreads();
    if (tid == 0) out[(size_t)Bg * OUTC] = (sred[0] + sred[1] + sred[2] + sred[3]) * (1.f / Bg);
}

extern "C" void kernel_launch(void* const* d_in, const int* in_sizes, int n_in,
                              void* d_out, int out_size, void* d_ws, size_t ws_size,
                              hipStream_t stream)
{
    const float* x    = (const float*)d_in[0];
    const int*   ei   = (const int*)  d_in[1];
    // d_in[2] = batch (unused: graphs are contiguous blocks of NPG nodes)
    const float* w_c1 = (const float*)d_in[3];
    const float* b_c1 = (const float*)d_in[4];
    const float* w_p1 = (const float*)d_in[5];
    const float* b_p1 = (const float*)d_in[6];
    const float* w2r  = (const float*)d_in[7];
    const float* b2   = (const float*)d_in[8];
    const float* w2o  = (const float*)d_in[9];
    const float* w_p2 = (const float*)d_in[10];
    const float* b_p2 = (const float*)d_in[11];
    const float* w3r  = (const float*)d_in[12];
    const float* b3   = (const float*)d_in[13];
    const float* w3o  = (const float*)d_in[14];
    const float* w_l1 = (const float*)d_in[15];
    const float* b_l1 = (const float*)d_in[16];
    const float* w_l2 = (const float*)d_in[17];
    const float* b_l2 = (const float*)d_in[18];
    float* out = (float*)d_out;
    float* wsg = (float*)d_ws;

    hipLaunchKernelGGL(mincut_fused, dim3(Bg), dim3(NT), 0, stream,
                       x, ei, w_c1, b_c1, w_p1, b_p1, w2r, b2, w2o,
                       w_p2, b_p2, w3r, b3, w3o, w_l1, b_l1, w_l2, b_l2,
                       out, wsg);
    hipLaunchKernelGGL(loss_reduce, dim3(1), dim3(NT), 0, stream, wsg, out);
}

// Round 5
// 286.124 us; speedup vs baseline: 1.3453x; 1.3453x over previous
//
#include <hip/hip_runtime.h>

#define NT 256

constexpr int Bg   = 8192;      // graphs
constexpr int NPG  = 40;        // nodes per graph
constexpr int EPG  = 640;       // edges per graph
constexpr int IN_  = 64;
constexpr int HID  = 32;
constexpr int K1   = 20;
constexpr int K2   = 10;
constexpr int OUTC = 10;
constexpr int NE   = Bg * NPG * 16;   // total edges
constexpr int SH   = 36;        // padded 32-wide row stride (floats)
constexpr float EPSF = 1e-15f;

#define FMA4(acc, a, b) do { \
    float _s = (a); \
    acc.x = fmaf(_s, (b).x, acc.x); \
    acc.y = fmaf(_s, (b).y, acc.y); \
    acc.z = fmaf(_s, (b).z, acc.z); \
    acc.w = fmaf(_s, (b).w, acc.w); } while (0)

__device__ __forceinline__ float wave_red(float v) {
#pragma unroll
    for (int off = 32; off > 0; off >>= 1) v += __shfl_down(v, off, 64);
    return v;
}

// LDS overlay map (floats):
//  sA_  [1600] : A raw (iv0-iv6) ; first 400 become A2 = S^T A S raw (iv7+)
//  bufH [1440] : H=XW1 (iv1-3) ; X2 [0..720) (iv7+, then X2new iv C+) ;
//                XW2r [720..1440) (iv8+)
//  bufXd[1440] : Xd (iv3-7) ; XW3r [0..360), XW3o [360..720) (ivI+) ;
//                X3 [720..1080) (ivF+) ; X4 [1080..1440) (ivJ+)
//  bufS [800]  : S1 (iv4-7) ; S2 [0..200), AS2 [200..400), A3 [400..500),
//                SS2 [500..600) (ivD+)
//  bufAS[800]  : AS=A@S (iv6-7) ; XW2o [0..720) (iv8+)
//  sSS  [400]  : S^T S (iv6-8)
// NOTE: __launch_bounds__(256,4) NOT (256,6) — the (256,6) variant forced the
// register allocator to 40 VGPRs and spilled ~38KB/block to scratch
// (WRITE_SIZE 6.8MB -> 313MB, dur +45%). LDS (26.6KB) already caps residency
// at 6 blocks/CU, so the looser bound costs nothing.
__global__ __launch_bounds__(NT, 4)
void mincut_fused(const float* __restrict__ x, const int* __restrict__ ei,
                  const float* __restrict__ w_c1, const float* __restrict__ b_c1,
                  const float* __restrict__ w_p1, const float* __restrict__ b_p1,
                  const float* __restrict__ w2r_, const float* __restrict__ b2_,
                  const float* __restrict__ w2o_,
                  const float* __restrict__ w_p2, const float* __restrict__ b_p2,
                  const float* __restrict__ w3r_, const float* __restrict__ b3_,
                  const float* __restrict__ w3o_,
                  const float* __restrict__ w_l1, const float* __restrict__ b_l1,
                  const float* __restrict__ w_l2, const float* __restrict__ b_l2,
                  float* __restrict__ out, float* __restrict__ wsg)
{
    __shared__ __align__(16) float sA_[NPG * NPG];   // 1600
    __shared__ __align__(16) float bufH[NPG * SH];   // 1440
    __shared__ __align__(16) float bufXd[NPG * SH];  // 1440
    __shared__ __align__(16) float bufS[NPG * K1];   // 800
    __shared__ __align__(16) float bufAS[NPG * K1];  // 800
    __shared__ __align__(16) float sSS[K1 * K1];     // 400
    __shared__ __align__(16) float sdinv[NPG];
    __shared__ __align__(16) float srowsA[NPG];
    __shared__ __align__(16) float srowm[NPG];
    __shared__ __align__(16) float sden[NPG];
    __shared__ __align__(16) float sred1[2];
    __shared__ __align__(16) float sred2[2];
    __shared__ __align__(16) float sc[8];

    float* sA2  = sA_;           // 20x20
    float* sX2  = bufH;          // 20xSH (X2, then X2new)
    float* sW2r = bufH + 720;    // 20xSH (X2 @ w2r)
    float* sW2o = bufAS;         // 20xSH (X2 @ w2o)
    float* sS2  = bufS;          // 20x10
    float* sAS2 = bufS + 200;    // 20x10
    float* sA3  = bufS + 400;    // 10x10
    float* sSS2 = bufS + 500;    // 10x10
    float* sW3r = bufXd;         // 10xSH
    float* sW3o = bufXd + 360;   // 10xSH
    float* sX3  = bufXd + 720;   // 10xSH
    float* sX4  = bufXd + 1080;  // 10xSH

    const int g    = blockIdx.x;
    const int tid  = threadIdx.x;
    const int lane = tid & 63;
    const int wid  = tid >> 6;

    // ---------------- iv0: zero A, load edges to regs ----------------
    int er0, ec0, er1, ec1, er2 = -1, ec2 = 0;
    {
        const int eb = g * EPG, nb = g * NPG;
        const int* srcp = ei;
        const int* dstp = ei + NE;
        int e = eb + tid;
        er0 = srcp[e] - nb; ec0 = dstp[e] - nb;
        e += NT;
        er1 = srcp[e] - nb; ec1 = dstp[e] - nb;
        if (tid + 2 * NT < EPG) {
            e += NT;
            er2 = srcp[e] - nb; ec2 = dstp[e] - nb;
        }
    }
    for (int i = tid; i < NPG * NPG; i += NT) sA_[i] = 0.f;
    __syncthreads();

    // ------- iv1: adj scatter + H = X @ W1 (X, W1 from global) -------
    atomicAdd(&sA_[er0 * NPG + ec0], 1.f);
    atomicAdd(&sA_[er1 * NPG + ec1], 1.f);
    if (er2 >= 0) atomicAdd(&sA_[er2 * NPG + ec2], 1.f);

    if (tid < 160) {                 // 20 row-pairs x 8 col-quads
        int np = tid >> 3, fq = tid & 7;
        int n0 = 2 * np, n1 = n0 + 1;
        const float4* x0 = (const float4*)(x + (size_t)g * (NPG * IN_) + n0 * IN_);
        const float4* x1 = (const float4*)(x + (size_t)g * (NPG * IN_) + n1 * IN_);
        const float4* wg = (const float4*)w_c1;
        float4 acc0 = {0.f,0.f,0.f,0.f}, acc1 = {0.f,0.f,0.f,0.f};
#pragma unroll 4
        for (int kk = 0; kk < IN_ / 4; kk++) {
            float4 a0 = x0[kk], a1 = x1[kk];
            float4 w0 = wg[(4*kk+0)*8 + fq];
            float4 w1 = wg[(4*kk+1)*8 + fq];
            float4 w2 = wg[(4*kk+2)*8 + fq];
            float4 w3 = wg[(4*kk+3)*8 + fq];
            FMA4(acc0, a0.x, w0); FMA4(acc0, a0.y, w1);
            FMA4(acc0, a0.z, w2); FMA4(acc0, a0.w, w3);
            FMA4(acc1, a1.x, w0); FMA4(acc1, a1.y, w1);
            FMA4(acc1, a1.z, w2); FMA4(acc1, a1.w, w3);
        }
        ((float4*)(bufH + n0 * SH))[fq] = acc0;
        ((float4*)(bufH + n1 * SH))[fq] = acc1;
    }
    __syncthreads();

    // ---------------- iv2: degrees ----------------
    if (tid < NPG) {                 // col sums -> dinv
        float s = 0.f;
#pragma unroll
        for (int r = 0; r < NPG; r++) s += sA_[r * NPG + tid];
        sdinv[tid] = rsqrtf(s + 1.f);
    } else if (tid >= 64 && tid < 64 + NPG) {   // row sums (d_flat, raw A)
        int n = tid - 64; float s = 0.f;
#pragma unroll
        for (int m = 0; m < NPG; m++) s += sA_[n * NPG + m];
        srowsA[n] = s;
    }
    __syncthreads();

    // ------- iv3: Xd = relu(D^-1/2 (A+I) D^-1/2 H + b1) [f2 A reads] -------
    if (tid < 160) {
        int cp = tid >> 3, fq = tid & 7;
        int c0 = 2 * cp, c1 = c0 + 1;
        float4 acc0 = {0.f,0.f,0.f,0.f}, acc1 = {0.f,0.f,0.f,0.f};
#pragma unroll 8
        for (int r = 0; r < NPG; r++) {
            float2 a2 = *(const float2*)&sA_[r * NPG + c0];
            float dv = sdinv[r];
            float4 b = ((const float4*)(bufH + r * SH))[fq];
            FMA4(acc0, a2.x * dv, b);
            FMA4(acc1, a2.y * dv, b);
        }
        float4 bb = ((const float4*)b_c1)[fq];
        float4 h0 = ((const float4*)(bufH + c0 * SH))[fq];
        float4 h1 = ((const float4*)(bufH + c1 * SH))[fq];
        float d0 = sdinv[c0], d1 = sdinv[c1];
        float4 r0, r1;
        r0.x = fmaxf(fmaf(d0, fmaf(d0, h0.x, acc0.x), bb.x), 0.f);
        r0.y = fmaxf(fmaf(d0, fmaf(d0, h0.y, acc0.y), bb.y), 0.f);
        r0.z = fmaxf(fmaf(d0, fmaf(d0, h0.z, acc0.z), bb.z), 0.f);
        r0.w = fmaxf(fmaf(d0, fmaf(d0, h0.w, acc0.w), bb.w), 0.f);
        r1.x = fmaxf(fmaf(d1, fmaf(d1, h1.x, acc1.x), bb.x), 0.f);
        r1.y = fmaxf(fmaf(d1, fmaf(d1, h1.y, acc1.y), bb.y), 0.f);
        r1.z = fmaxf(fmaf(d1, fmaf(d1, h1.z, acc1.z), bb.z), 0.f);
        r1.w = fmaxf(fmaf(d1, fmaf(d1, h1.w, acc1.w), bb.w), 0.f);
        ((float4*)(bufXd + c0 * SH))[fq] = r0;
        ((float4*)(bufXd + c1 * SH))[fq] = r1;
    }
    __syncthreads();

    // ---------------- iv4: S1 logits = Xd @ Wp1 + bp1 ----------------
    if (tid < 100) {                 // 20 row-pairs x 5 l-quads
        int np = tid / 5, lq = tid - np * 5;
        int n0 = 2 * np, n1 = n0 + 1;
        const float4* wg = (const float4*)w_p1;
        float4 bb = ((const float4*)b_p1)[lq];
        float4 acc0 = bb, acc1 = bb;
#pragma unroll 8
        for (int k = 0; k < HID; k++) {
            float a0 = bufXd[n0 * SH + k];
            float a1 = bufXd[n1 * SH + k];
            float4 w = wg[k * 5 + lq];
            FMA4(acc0, a0, w);
            FMA4(acc1, a1, w);
        }
        ((float4*)(bufS + n0 * K1))[lq] = acc0;
        ((float4*)(bufS + n1 * K1))[lq] = acc1;
    }
    __syncthreads();

    // ---------------- iv5: row softmax (K1) ----------------
    if (tid < NPG) {
        float* row = bufS + tid * K1;
        float v[K1]; float m = -3.0e38f;
#pragma unroll
        for (int k = 0; k < K1; k++) { v[k] = row[k]; m = fmaxf(m, v[k]); }
        float ssum = 0.f;
#pragma unroll
        for (int k = 0; k < K1; k++) { v[k] = __expf(v[k] - m); ssum += v[k]; }
        float inv = 1.f / ssum;
#pragma unroll
        for (int k = 0; k < K1; k++) row[k] = v[k] * inv;
    }
    __syncthreads();

    // ---------------- iv6: AS = A @ S [f4 A-rows] ; SS = S^T S [f2] --------
    if (tid < 100) {                 // AS: 20 row-pairs x 5 quads
        int np = tid / 5, lq = tid - np * 5;
        int n0 = 2 * np, n1 = n0 + 1;
        const float4* sb = (const float4*)bufS;
        float4 acc0 = {0.f,0.f,0.f,0.f}, acc1 = {0.f,0.f,0.f,0.f};
#pragma unroll
        for (int m4 = 0; m4 < NPG / 4; m4++) {
            float4 a0 = *(const float4*)&sA_[n0 * NPG + 4 * m4];
            float4 a1 = *(const float4*)&sA_[n1 * NPG + 4 * m4];
            float4 b0 = sb[(4*m4+0)*5 + lq];
            float4 b1 = sb[(4*m4+1)*5 + lq];
            float4 b2v = sb[(4*m4+2)*5 + lq];
            float4 b3v = sb[(4*m4+3)*5 + lq];
            FMA4(acc0, a0.x, b0); FMA4(acc0, a0.y, b1);
            FMA4(acc0, a0.z, b2v); FMA4(acc0, a0.w, b3v);
            FMA4(acc1, a1.x, b0); FMA4(acc1, a1.y, b1);
            FMA4(acc1, a1.z, b2v); FMA4(acc1, a1.w, b3v);
        }
        ((float4*)(bufAS + n0 * K1))[lq] = acc0;
        ((float4*)(bufAS + n1 * K1))[lq] = acc1;
    } else if (tid < 150) {          // SS: 10 k-pairs x 5 quads
        int oo = tid - 100;
        int kp = oo / 5, lq = oo - kp * 5;
        int k0 = 2 * kp, k1 = k0 + 1;
        float4 acc0 = {0.f,0.f,0.f,0.f}, acc1 = {0.f,0.f,0.f,0.f};
#pragma unroll 8
        for (int n = 0; n < NPG; n++) {
            float2 s2v = *(const float2*)&bufS[n * K1 + k0];
            float4 b = ((const float4*)(bufS + n * K1))[lq];
            FMA4(acc0, s2v.x, b);
            FMA4(acc1, s2v.y, b);
        }
        ((float4*)(sSS + k0 * K1))[lq] = acc0;
        ((float4*)(sSS + k1 * K1))[lq] = acc1;
    }
    __syncthreads();

    // --- iv7: A2 = S^T AS ; X2 = S^T Xd ; den1 terms ; SS-Frob (wave3) ----
    if (tid < 50) {                  // A2: 10 k-pairs x 5 quads
        int kp = tid / 5, lq = tid - kp * 5;
        int k0 = 2 * kp, k1 = k0 + 1;
        float4 acc0 = {0.f,0.f,0.f,0.f}, acc1 = {0.f,0.f,0.f,0.f};
#pragma unroll 8
        for (int n = 0; n < NPG; n++) {
            float2 s2v = *(const float2*)&bufS[n * K1 + k0];
            float4 b = ((const float4*)(bufAS + n * K1))[lq];
            FMA4(acc0, s2v.x, b);
            FMA4(acc1, s2v.y, b);
        }
        ((float4*)(sA2 + k0 * K1))[lq] = acc0;
        ((float4*)(sA2 + k1 * K1))[lq] = acc1;
    } else if (tid < 130) {          // X2: 10 k-pairs x 8 f-quads
        int oo = tid - 50;
        int kp = oo >> 3, fq = oo & 7;
        int k0 = 2 * kp, k1 = k0 + 1;
        float4 acc0 = {0.f,0.f,0.f,0.f}, acc1 = {0.f,0.f,0.f,0.f};
#pragma unroll 8
        for (int n = 0; n < NPG; n++) {
            float2 s2v = *(const float2*)&bufS[n * K1 + k0];
            float4 b = ((const float4*)(bufXd + n * SH))[fq];
            FMA4(acc0, s2v.x, b);
            FMA4(acc1, s2v.y, b);
        }
        ((float4*)(sX2 + k0 * SH))[fq] = acc0;
        ((float4*)(sX2 + k1 * SH))[fq] = acc1;
    } else if (tid < 170) {          // den1 terms
        int n = tid - 130;
        float s2 = 0.f;
#pragma unroll
        for (int k = 0; k < K1; k++) { float v = bufS[n * K1 + k]; s2 = fmaf(v, v, s2); }
        sden[n] = srowsA[n] * s2;
    } else if (wid == 3) {           // ||SS||_F^2 -> sc[2]
        float v = 0.f;
        for (int i = lane; i < K1 * K1; i += 64) { float t = sSS[i]; v = fmaf(t, t, v); }
        v = wave_red(v); if (lane == 0) sc[2] = v;
    }
    __syncthreads();

    // --- iv8: ortho1 (w0,w1) ; trace1+rownorm1 (w2) ; den1-red (w3) ;
    //          then all threads: XW2r = X2@w2r, XW2o = X2@w2o --------------
    if (wid < 2) {
        float rn = 1.f / sqrtf(sc[2]);
        const float isk = 0.22360679774997896f;   // 1/sqrt(20)
        float p = 0.f;
        for (int o = tid; o < K1 * K1; o += 128) {
            int k = o / K1, l = o - k * K1;
            float v = sSS[o] * rn - ((k == l) ? isk : 0.f);
            p = fmaf(v, v, p);
        }
        p = wave_red(p);
        if (lane == 0) sred1[wid] = p;
    } else if (wid == 2) {
        float v = (lane < K1) ? sA2[lane * (K1 + 1)] : 0.f;
        v = wave_red(v); if (lane == 0) sc[0] = v;          // num1 = trace
        if (lane < K1) {            // row norms of diag-zeroed A2 (raw kept)
            float s = 0.f;
#pragma unroll
            for (int l = 0; l < K1; l++) s += sA2[lane * K1 + l];
            s -= sA2[lane * (K1 + 1)];
            srowm[lane] = 1.f / (sqrtf(s) + EPSF);
        }
    } else {
        float v = (lane < NPG) ? sden[lane] : 0.f;
        v = wave_red(v); if (lane == 0) sc[1] = v;          // den1
    }
    for (int o = tid; o < 320; o += NT) {    // 1-row x 8fq, two matmuls
        bool first = (o < 160);
        int oo = first ? o : o - 160;
        int n = oo >> 3, fq = oo & 7;
        const float4* wg = (const float4*)(first ? w2r_ : w2o_);
        float4 acc = {0.f,0.f,0.f,0.f};
#pragma unroll 8
        for (int k = 0; k < HID; k++) {
            float a = sX2[n * SH + k];
            FMA4(acc, a, wg[k * 8 + fq]);
        }
        if (first) ((float4*)(sW2r + n * SH))[fq] = acc;
        else       ((float4*)(sW2o + n * SH))[fq] = acc;
    }
    __syncthreads();

    // --- ivC: X2' = relu(adj1n @ XW2r + XW2o + b2)  [norm folded, diag=0] --
    if (tid < 80) {
        int kp = tid >> 3, fq = tid & 7;
        int k0 = 2 * kp, k1 = k0 + 1;
        float4 acc0 = {0.f,0.f,0.f,0.f}, acc1 = {0.f,0.f,0.f,0.f};
#pragma unroll
        for (int l = 0; l < K1; l++) {
            float rl = srowm[l];
            float a0 = (l == k0) ? 0.f : sA2[k0 * K1 + l];
            float a1 = (l == k1) ? 0.f : sA2[k1 * K1 + l];
            float4 w = ((const float4*)(sW2r + l * SH))[fq];
            FMA4(acc0, a0 * rl, w);
            FMA4(acc1, a1 * rl, w);
        }
        float4 bb = ((const float4*)b2_)[fq];
        float4 o0 = ((const float4*)(sW2o + k0 * SH))[fq];
        float4 o1 = ((const float4*)(sW2o + k1 * SH))[fq];
        float rk0 = srowm[k0], rk1 = srowm[k1];
        float4 r0, r1;
        r0.x = fmaxf(fmaf(rk0, acc0.x, o0.x + bb.x), 0.f);
        r0.y = fmaxf(fmaf(rk0, acc0.y, o0.y + bb.y), 0.f);
        r0.z = fmaxf(fmaf(rk0, acc0.z, o0.z + bb.z), 0.f);
        r0.w = fmaxf(fmaf(rk0, acc0.w, o0.w + bb.w), 0.f);
        r1.x = fmaxf(fmaf(rk1, acc1.x, o1.x + bb.x), 0.f);
        r1.y = fmaxf(fmaf(rk1, acc1.y, o1.y + bb.y), 0.f);
        r1.z = fmaxf(fmaf(rk1, acc1.z, o1.z + bb.z), 0.f);
        r1.w = fmaxf(fmaf(rk1, acc1.w, o1.w + bb.w), 0.f);
        ((float4*)(sX2 + k0 * SH))[fq] = r0;    // overwrite X2 with X2'
        ((float4*)(sX2 + k1 * SH))[fq] = r1;
    }
    __syncthreads();

    // ---------------- ivD: S2 logits ----------------
    if (tid < K1 * K2) {
        int n = tid / K2, q = tid - n * K2;
        float acc = b_p2[q];
#pragma unroll 8
        for (int j = 0; j < HID; j++) acc = fmaf(sX2[n * SH + j], w_p2[j * K2 + q], acc);
        sS2[tid] = acc;
    }
    __syncthreads();

    // ---------------- ivE: softmax2 ----------------
    if (tid < K1) {
        float* row = sS2 + tid * K2;
        float v[K2]; float m = -3.0e38f;
#pragma unroll
        for (int q = 0; q < K2; q++) { v[q] = row[q]; m = fmaxf(m, v[q]); }
        float ssum = 0.f;
#pragma unroll
        for (int q = 0; q < K2; q++) { v[q] = __expf(v[q] - m); ssum += v[q]; }
        float inv = 1.f / ssum;
#pragma unroll
        for (int q = 0; q < K2; q++) row[q] = v[q] * inv;
    }
    __syncthreads();

    // --- ivF: AS2 = adj1n@S2 [folded] ; SS2 ; X3 = S2^T X2' ; den2 terms ---
    for (int o = tid; o < 400; o += NT) {
        if (o < 200) {
            int n = o / K2, l = o - n * K2;
            float acc = 0.f;
#pragma unroll
            for (int m = 0; m < K1; m++) {
                float a = (m == n) ? 0.f : sA2[n * K1 + m];
                acc = fmaf(a * srowm[m], sS2[m * K2 + l], acc);
            }
            sAS2[n * K2 + l] = acc * srowm[n];
        } else if (o < 300) {
            int oo = o - 200; int k = oo / K2, l = oo - k * K2;
            float acc = 0.f;
#pragma unroll
            for (int n = 0; n < K1; n++) acc = fmaf(sS2[n * K2 + k], sS2[n * K2 + l], acc);
            sSS2[k * K2 + l] = acc;
        } else if (o < 380) {
            int oo = o - 300; int k = oo >> 3, fq = oo & 7;
            float4 acc = {0.f, 0.f, 0.f, 0.f};
#pragma unroll
            for (int n = 0; n < K1; n++) {
                float a = sS2[n * K2 + k];
                float4 b = ((const float4*)(sX2 + n * SH))[fq];
                FMA4(acc, a, b);
            }
            ((float4*)(sX3 + k * SH))[fq] = acc;
        } else {
            int n = o - 380;          // d_flat of adj1n times ||S2 row||^2
            float da = 0.f, s2 = 0.f;
#pragma unroll
            for (int l = 0; l < K1; l++) {
                float a = (l == n) ? 0.f : sA2[n * K1 + l];
                da = fmaf(a, srowm[l], da);
            }
            da *= srowm[n];
#pragma unroll
            for (int q = 0; q < K2; q++) { float v = sS2[n * K2 + q]; s2 = fmaf(v, v, s2); }
            sden[n] = da * s2;
        }
    }
    __syncthreads();

    // --- ivG: out_adj2 = S2^T AS2 ; den2-red (w2) ; SS2-Frob (w3) ---------
    if (tid < K2 * K2) {
        int k = tid / K2, l = tid - k * K2;
        float acc = 0.f;
#pragma unroll
        for (int n = 0; n < K1; n++) acc = fmaf(sS2[n * K2 + k], sAS2[n * K2 + l], acc);
        sA3[tid] = acc;
    } else if (wid == 2) {
        float v = (lane < K1) ? sden[lane] : 0.f;
        v = wave_red(v); if (lane == 0) sc[5] = v;          // den2
    } else if (wid == 3) {
        float v = 0.f;
        for (int i = lane; i < K2 * K2; i += 64) { float t = sSS2[i]; v = fmaf(t, t, v); }
        v = wave_red(v); if (lane == 0) sc[6] = v;          // ||SS2||_F^2
    }
    __syncthreads();

    // --- ivH: ortho2 (w0) ; trace2 + rownorm2 (w1) ------------------------
    if (wid == 0) {
        float rn = 1.f / sqrtf(sc[6]);
        const float isk = 0.31622776601683794f;   // 1/sqrt(10)
        float p = 0.f;
        for (int i = lane; i < K2 * K2; i += 64) {
            int k = i / K2, l = i - k * K2;
            float v = sSS2[i] * rn - ((k == l) ? isk : 0.f);
            p = fmaf(v, v, p);
        }
        p = wave_red(p);
        if (lane == 0) sred2[0] = p;
    } else if (wid == 1) {
        float v = (lane < K2) ? sA3[lane * (K2 + 1)] : 0.f;
        v = wave_red(v); if (lane == 0) sc[4] = v;          // num2 = trace
        if (lane < K2) {
            float s = 0.f;
#pragma unroll
            for (int l = 0; l < K2; l++) s += sA3[lane * K2 + l];
            s -= sA3[lane * (K2 + 1)];
            srowm[lane] = 1.f / (sqrtf(s) + EPSF);
        }
    }
    __syncthreads();

    // --- ivI: XW3r = X3@w3r ; XW3o = X3@w3o ; loss write ------------------
    if (tid < 160) {
        bool first = (tid < 80);
        int oo = first ? tid : tid - 80;
        int n = oo >> 3, fq = oo & 7;
        const float4* wg = (const float4*)(first ? w3r_ : w3o_);
        float4 acc = {0.f,0.f,0.f,0.f};
#pragma unroll 8
        for (int k = 0; k < HID; k++) {
            float a = sX3[n * SH + k];
            FMA4(acc, a, wg[k * 8 + fq]);
        }
        if (first) ((float4*)(sW3r + n * SH))[fq] = acc;
        else       ((float4*)(sW3o + n * SH))[fq] = acc;
    } else if (tid == 200) {
        float o1 = sqrtf(sred1[0] + sred1[1]);
        float o2 = sqrtf(sred2[0]);
        wsg[g] = -(sc[0] / sc[1]) + o1 - (sc[4] / sc[5]) + o2;
    }
    __syncthreads();

    // --- ivJ: X4 = adj2n @ XW3r + XW3o + b3 [folded norm, diag=0] ---------
    if (tid < 40) {
        int kp = tid >> 3, fq = tid & 7;
        int k0 = 2 * kp, k1 = k0 + 1;
        float4 acc0 = {0.f,0.f,0.f,0.f}, acc1 = {0.f,0.f,0.f,0.f};
#pragma unroll
        for (int l = 0; l < K2; l++) {
            float rl = srowm[l];
            float a0 = (l == k0) ? 0.f : sA3[k0 * K2 + l];
            float a1 = (l == k1) ? 0.f : sA3[k1 * K2 + l];
            float4 w = ((const float4*)(sW3r + l * SH))[fq];
            FMA4(acc0, a0 * rl, w);
            FMA4(acc1, a1 * rl, w);
        }
        float4 bb = ((const float4*)b3_)[fq];
        float4 o0 = ((const float4*)(sW3o + k0 * SH))[fq];
        float4 o1 = ((const float4*)(sW3o + k1 * SH))[fq];
        float rk0 = srowm[k0], rk1 = srowm[k1];
        float4 r0, r1;
        r0.x = fmaf(rk0, acc0.x, o0.x + bb.x);
        r0.y = fmaf(rk0, acc0.y, o0.y + bb.y);
        r0.z = fmaf(rk0, acc0.z, o0.z + bb.z);
        r0.w = fmaf(rk0, acc0.w, o0.w + bb.w);
        r1.x = fmaf(rk1, acc1.x, o1.x + bb.x);
        r1.y = fmaf(rk1, acc1.y, o1.y + bb.y);
        r1.z = fmaf(rk1, acc1.z, o1.z + bb.z);
        r1.w = fmaf(rk1, acc1.w, o1.w + bb.w);
        ((float4*)(sX4 + k0 * SH))[fq] = r0;
        ((float4*)(sX4 + k1 * SH))[fq] = r1;
    }
    __syncthreads();

    // --- ivK: mean pool + MLP head, single wave, shuffle-based ------------
    if (wid == 0) {
        int f = lane & 31;
        float pool = 0.f;
#pragma unroll
        for (int n = 0; n < K2; n++) pool += sX4[n * SH + f];
        pool *= (1.f / K2);
        float acc = b_l1[f];
#pragma unroll
        for (int j = 0; j < HID; j++)
            acc = fmaf(__shfl(pool, j, 64), w_l1[j * HID + f], acc);
        float t1 = fmaxf(acc, 0.f);
        int o = (lane < OUTC) ? lane : 0;
        float acc2 = b_l2[o];
#pragma unroll
        for (int j = 0; j < HID; j++)
            acc2 = fmaf(__shfl(t1, j, 64), w_l2[j * OUTC + o], acc2);
        if (lane < OUTC) out[(size_t)g * OUTC + lane] = acc2;
    }
}

__global__ void loss_reduce(const float* __restrict__ wsg, float* __restrict__ out)
{
    __shared__ float sred[4];
    int tid = threadIdx.x;
    float s = 0.f;
    for (int i = tid; i < Bg; i += NT) s += wsg[i];
    s = wave_red(s);
    if ((tid & 63) == 0) sred[tid >> 6] = s;
    __syncthreads();
    if (tid == 0) out[(size_t)Bg * OUTC] = (sred[0] + sred[1] + sred[2] + sred[3]) * (1.f / Bg);
}

extern "C" void kernel_launch(void* const* d_in, const int* in_sizes, int n_in,
                              void* d_out, int out_size, void* d_ws, size_t ws_size,
                              hipStream_t stream)
{
    const float* x    = (const float*)d_in[0];
    const int*   ei   = (const int*)  d_in[1];
    // d_in[2] = batch (unused: graphs are contiguous blocks of NPG nodes)
    const float* w_c1 = (const float*)d_in[3];
    const float* b_c1 = (const float*)d_in[4];
    const float* w_p1 = (const float*)d_in[5];
    const float* b_p1 = (const float*)d_in[6];
    const float* w2r  = (const float*)d_in[7];
    const float* b2   = (const float*)d_in[8];
    const float* w2o  = (const float*)d_in[9];
    const float* w_p2 = (const float*)d_in[10];
    const float* b_p2 = (const float*)d_in[11];
    const float* w3r  = (const float*)d_in[12];
    const float* b3   = (const float*)d_in[13];
    const float* w3o  = (const float*)d_in[14];
    const float* w_l1 = (const float*)d_in[15];
    const float* b_l1 = (const float*)d_in[16];
    const float* w_l2 = (const float*)d_in[17];
    const float* b_l2 = (const float*)d_in[18];
    float* out = (float*)d_out;
    float* wsg = (float*)d_ws;

    hipLaunchKernelGGL(mincut_fused, dim3(Bg), dim3(NT), 0, stream,
                       x, ei, w_c1, b_c1, w_p1, b_p1, w2r, b2, w2o,
                       w_p2, b_p2, w3r, b3, w3o, w_l1, b_l1, w_l2, b_l2,
                       out, wsg);
    hipLaunchKernelGGL(loss_reduce, dim3(1), dim3(NT), 0, stream, wsg, out);
}